// Round 4
// baseline (1159.450 us; speedup 1.0000x reference)
//
#include <hip/hip_runtime.h>

#define EMBD 300
#define NSTEP 300
#define HID 512
#define G4 2048
#define TPB 256
#define NTEAM 32          // WGs in the working team (target: 32 CUs = one XCD)
#define NWG_SCAN 512      // oversubscribed grid for the election

#define TS2 15            // steps per phase-1 step-group
#define NSG 20            // step groups (20*15 = 300)
#define NRG 8             // row groups (8*256 = 2048 rows)

#define SENTINEL 0xFFC00000u   // quiet NaN: h values are always finite

// ws float layout:
//   [0 .. 614400)   : X_proj [300][2048]
//   [.. +154112)    : HSEQ [301][512]  (h state before each step)
//   [.. +16)        : election state: [0..7] team counters, [8] winner (0xFFFFFFFF)
#define XP_SZ    (NSTEP * G4)
#define HSEQ_OFF XP_SZ
#define HSEQ_SZ  ((NSTEP + 1) * HID)
#define ELECT_OFF (HSEQ_OFF + HSEQ_SZ)

__device__ __forceinline__ float fsig(float x) { return 1.0f / (1.0f + __expf(-x)); }
__device__ __forceinline__ float ftanh(float x) {
    x = fminf(15.0f, fmaxf(-15.0f, x));
    float t = __expf(2.0f * x);
    return (t - 1.0f) / (t + 1.0f);
}

// L1-bypass load (served by the XCD-shared L2 when the line is local).
__device__ __forceinline__ unsigned long long load2_sc0(const void* p) {
    unsigned long long v;
    asm volatile("global_load_dwordx2 %0, %1, off sc0\n\ts_waitcnt vmcnt(0)"
                 : "=v"(v) : "v"(p) : "memory");
    return v;
}
__device__ __forceinline__ void store1_sc0(void* p, unsigned v) {
    asm volatile("global_store_dword %0, %1, off sc0" :: "v"(p), "v"(v) : "memory");
}
__device__ __forceinline__ bool has_sent(unsigned long long v) {
    return ((unsigned)v == SENTINEL) || ((unsigned)(v >> 32) == SENTINEL);
}

// Phase 1: X_proj[t][r] = b_ih[r]+b_hh[r] + sum_e W_ih[r][e]*emb[x[t]][e]
// Grid (NRG, NSG). Also sentinel-clears HSEQ rows 1..300, copies h0 into
// HSEQ[0], re-inits election state (every call -> replay-safe). Kernel-end
// L2 flush makes all of it globally visible to phase 2.
__global__ __launch_bounds__(TPB) void xproj_init_kernel(
    const int* __restrict__ x, const float* __restrict__ h0,
    const float* __restrict__ emb, const float* __restrict__ W_ih,
    const float* __restrict__ b_ih, const float* __restrict__ b_hh,
    float* __restrict__ ws) {
    const int rowg = blockIdx.x;      // 0..7
    const int sg   = blockIdx.y;      // 0..19
    const int tid  = threadIdx.x;
    const int t0   = sg * TS2;
    const int r    = rowg * TPB + tid;

    float* hseq = ws + HSEQ_OFF;

    if (rowg == 0) {
        unsigned* hs = (unsigned*)(hseq + (size_t)(t0 + 1) * HID);
        for (int i = tid; i < TS2 * HID; i += TPB) hs[i] = SENTINEL;
        if (sg == 0) {
            for (int i = tid; i < HID; i += TPB) hseq[i] = h0[i];
            if (tid < 16) {
                unsigned* el = (unsigned*)(ws + ELECT_OFF);
                el[tid] = (tid == 8) ? 0xFFFFFFFFu : 0u;
            }
        }
    }

    __shared__ float e_lds[TS2][EMBD];
    for (int tt = 0; tt < TS2; ++tt) {
        const float* er = emb + (long long)x[t0 + tt] * EMBD;
        for (int i = tid; i < EMBD; i += TPB) e_lds[tt][i] = er[i];
    }
    __syncthreads();

    float acc[TS2];
    const float bsum = b_ih[r] + b_hh[r];
    #pragma unroll
    for (int tt = 0; tt < TS2; ++tt) acc[tt] = bsum;

    const float* wrow = W_ih + (size_t)r * EMBD;
    for (int e = 0; e < EMBD; e += 4) {
        const float4 w4 = *(const float4*)(wrow + e);
        #pragma unroll
        for (int tt = 0; tt < TS2; ++tt) {
            acc[tt] = fmaf(w4.x, e_lds[tt][e],     acc[tt]);
            acc[tt] = fmaf(w4.y, e_lds[tt][e + 1], acc[tt]);
            acc[tt] = fmaf(w4.z, e_lds[tt][e + 2], acc[tt]);
            acc[tt] = fmaf(w4.w, e_lds[tt][e + 3], acc[tt]);
        }
    }
    #pragma unroll
    for (int tt = 0; tt < TS2; ++tt)
        ws[(size_t)(t0 + tt) * G4 + r] = acc[tt];
}

// Phase 2: persistent dataflow scan with XCD-team election.
// 512 WGs; each joins a team keyed by HW_REG_XCC_ID; first team to 32 members
// wins (pigeonhole over >=512 resident WGs guarantees some team fills); the
// rest exit. Exchange is hang-proof: producers store h with BOTH an sc0 store
// (fast same-XCD L2 visibility) and an agent-scope store (guaranteed global
// visibility); consumers poll with sc0 loads but every 8th poll is an
// agent-scope load, so progress is guaranteed even if the team is mixed-XCD.
__global__ __launch_bounds__(TPB, 1) void lstm_scan_kernel(
    const float* __restrict__ c0, const float* __restrict__ W_hh,
    const float* __restrict__ fc_w, const float* __restrict__ fc_b,
    float* __restrict__ ws, float* __restrict__ out) {
    const int tid  = threadIdx.x;

    __shared__ int s_slot;
    __shared__ int s_win;

    unsigned* el = (unsigned*)(ws + ELECT_OFF);
    if (tid == 0) {
        unsigned xcd;
        asm volatile("s_getreg_b32 %0, hwreg(HW_REG_XCC_ID)" : "=s"(xcd));
        xcd &= 7u;
        const unsigned slot = __hip_atomic_fetch_add(&el[xcd], 1u,
                                  __ATOMIC_RELAXED, __HIP_MEMORY_SCOPE_AGENT);
        if (slot == NTEAM - 1) {
            unsigned expect = 0xFFFFFFFFu;
            __hip_atomic_compare_exchange_strong(&el[8], &expect, xcd,
                __ATOMIC_RELAXED, __ATOMIC_RELAXED, __HIP_MEMORY_SCOPE_AGENT);
        }
        int win = 0, sl = -1;
        if (slot < NTEAM) {
            unsigned w;
            do {
                w = __hip_atomic_load(&el[8], __ATOMIC_RELAXED, __HIP_MEMORY_SCOPE_AGENT);
                if (w == 0xFFFFFFFFu) __builtin_amdgcn_s_sleep(8);
            } while (w == 0xFFFFFFFFu);
            win = (w == xcd);
            sl = (int)slot;
        }
        s_win = win;
        s_slot = sl;
    }
    __syncthreads();
    if (!s_win) return;
    const int wg = s_slot;

    const int v    = tid >> 6;     // wave id
    const int lane = tid & 63;
    const int g    = lane >> 4;    // group within wave
    const int li   = lane & 15;    // lane within group (column split)
    const int hidx = wg * 16 + v * 4 + g;

    float* hseq     = ws + HSEQ_OFF;        // [301][512]
    const float* xp = ws;                   // [300][2048]

    __shared__ __align__(16) float h_lds[576];   // idx i -> i + 4*(i>>5)

    // W_hh slice in registers: wreg[gate][k] = W_hh[gate*512 + hidx][li*32 + k]
    float wreg[4][32];
    #pragma unroll
    for (int gate = 0; gate < 4; ++gate) {
        const float* wr = W_hh + ((size_t)gate * HID + hidx) * HID + li * 32;
        #pragma unroll
        for (int k = 0; k < 32; k += 4) {
            const float4 w4 = *(const float4*)(wr + k);
            wreg[gate][k] = w4.x; wreg[gate][k + 1] = w4.y;
            wreg[gate][k + 2] = w4.z; wreg[gate][k + 3] = w4.w;
        }
    }

    const bool upd = (li == 0);
    float c = upd ? c0[hidx] : 0.0f;

    for (int s = 0; s < NSTEP; ++s) {
        // X_proj loads issued before the poll -> latency hidden under it.
        float xi = 0.f, xf = 0.f, xg = 0.f, xo = 0.f;
        if (upd) {
            const float* xpt = xp + (size_t)s * G4 + hidx;
            xi = xpt[0]; xf = xpt[HID]; xg = xpt[2 * HID]; xo = xpt[3 * HID];
        }

        // Hybrid poll of this step's h words (8 B per thread).
        const unsigned* hb2 = (const unsigned*)(hseq + (size_t)s * HID) + 2 * tid;
        unsigned long long hv = load2_sc0(hb2);
        for (int k = 1; has_sent(hv); ++k) {
            if ((k & 7) == 0)
                hv = __hip_atomic_load((const unsigned long long*)hb2,
                                       __ATOMIC_RELAXED, __HIP_MEMORY_SCOPE_AGENT);
            else
                hv = load2_sc0(hb2);
        }
        {
            const int i0 = 2 * tid;
            float2* dst = (float2*)&h_lds[i0 + ((i0 >> 5) << 2)];
            *dst = make_float2(__uint_as_float((unsigned)hv),
                               __uint_as_float((unsigned)(hv >> 32)));
        }
        __syncthreads();   // all h_lds writes visible before any lane reads

        // 4 gate rows for hidx: 32 cols/lane + 4-stage butterfly.
        float sums[4];
        const float* hrow = &h_lds[li * 36];
        #pragma unroll
        for (int gate = 0; gate < 4; ++gate) {
            float acc = 0.0f;
            #pragma unroll
            for (int k = 0; k < 32; k += 4) {
                const float4 h4 = *(const float4*)(hrow + k);
                acc = fmaf(wreg[gate][k],     h4.x, acc);
                acc = fmaf(wreg[gate][k + 1], h4.y, acc);
                acc = fmaf(wreg[gate][k + 2], h4.z, acc);
                acc = fmaf(wreg[gate][k + 3], h4.w, acc);
            }
            acc += __shfl_xor(acc, 1);
            acc += __shfl_xor(acc, 2);
            acc += __shfl_xor(acc, 4);
            acc += __shfl_xor(acc, 8);
            sums[gate] = acc;
        }
        // No end-of-loop barrier: a wave can only overwrite h_lds for step s+1
        // after detecting step-s+1 data, which requires every group's reduce
        // (hence every lane's LDS reads of step s) to have completed.

        if (upd) {
            const float iv = fsig(sums[0] + xi);
            const float fv = fsig(sums[1] + xf);
            const float gv = ftanh(sums[2] + xg);
            const float ov = fsig(sums[3] + xo);
            c = fv * c + iv * gv;
            const float h = ov * ftanh(c);
            unsigned* dst = (unsigned*)(hseq + (size_t)(s + 1) * HID + hidx);
            const unsigned hbits = __float_as_uint(h);
            store1_sc0(dst, hbits);                       // fast same-XCD path
            __hip_atomic_store(dst, hbits, __ATOMIC_RELAXED,
                               __HIP_MEMORY_SCOPE_AGENT); // guaranteed path
            if (s == NSTEP - 1) {
                out[1 + hidx] = h;
                out[1 + HID + hidx] = c;
            }
        }
    }

    // Epilogue: team slot 0 computes out[0] = sigmoid(fc_w . h_300 + fc_b).
    if (wg == 0) {
        __syncthreads();
        const unsigned* hf = (const unsigned*)(hseq + (size_t)NSTEP * HID);
        unsigned long long va = load2_sc0(hf + 2 * tid);
        for (int k = 1; has_sent(va); ++k) {
            if ((k & 7) == 0)
                va = __hip_atomic_load((const unsigned long long*)(hf + 2 * tid),
                                       __ATOMIC_RELAXED, __HIP_MEMORY_SCOPE_AGENT);
            else
                va = load2_sc0(hf + 2 * tid);
        }
        const float p = __uint_as_float((unsigned)va) * fc_w[2 * tid]
                      + __uint_as_float((unsigned)(va >> 32)) * fc_w[2 * tid + 1];
        h_lds[tid] = p;
        __syncthreads();
        for (int off = 128; off > 0; off >>= 1) {
            if (tid < off) h_lds[tid] += h_lds[tid + off];
            __syncthreads();
        }
        if (tid == 0) out[0] = fsig(h_lds[0] + fc_b[0]);
    }
}

extern "C" void kernel_launch(void* const* d_in, const int* in_sizes, int n_in,
                              void* d_out, int out_size, void* d_ws, size_t ws_size,
                              hipStream_t stream) {
    (void)in_sizes; (void)n_in; (void)out_size; (void)ws_size;
    const int*   x     = (const int*)d_in[0];
    const float* h0    = (const float*)d_in[1];
    const float* c0    = (const float*)d_in[2];
    const float* emb   = (const float*)d_in[3];
    const float* W_ih  = (const float*)d_in[4];
    const float* W_hh  = (const float*)d_in[5];
    const float* b_ih  = (const float*)d_in[6];
    const float* b_hh  = (const float*)d_in[7];
    const float* fc_w  = (const float*)d_in[8];
    const float* fc_b  = (const float*)d_in[9];
    float* out = (float*)d_out;
    float* ws  = (float*)d_ws;

    xproj_init_kernel<<<dim3(NRG, NSG), dim3(TPB), 0, stream>>>(
        x, h0, emb, W_ih, b_ih, b_hh, ws);
    lstm_scan_kernel<<<dim3(NWG_SCAN), dim3(TPB), 0, stream>>>(
        c0, W_hh, fc_w, fc_b, ws, out);
}

// Round 5
// 827.982 us; speedup vs baseline: 1.4003x; 1.4003x over previous
//
#include <hip/hip_runtime.h>

#define EMBD 300
#define NSTEP 300
#define HID 512
#define G4 2048
#define TPB 256
#define NWG 32
#define NMB 8               // h replicas (mailboxes) per step

#define TS2 15              // steps per phase-1 step-group
#define NSG 20              // step groups (20*15 = 300)
#define NRG 8               // row groups (8*256 = 2048 rows)

#define SENTINEL 0xFFC00000u   // quiet NaN: h values are always finite

// ws float layout:
//   [0 .. 614400)        : X_proj [300][2048]
//   [614400 .. +301*4096): MB [301][NMB][512]  (replicated h per step)
#define XP_SZ   (NSTEP * G4)
#define MB_OFF  XP_SZ
#define MB_STEP (NMB * HID)     // 4096 floats per step

typedef unsigned uint4v __attribute__((ext_vector_type(4)));

__device__ __forceinline__ float fsig(float x) { return 1.0f / (1.0f + __expf(-x)); }
__device__ __forceinline__ float ftanh(float x) {
    x = fminf(15.0f, fmaxf(-15.0f, x));
    float t = __expf(2.0f * x);
    return (t - 1.0f) / (t + 1.0f);
}

// 32B agent-class load (bypass L1/L2 -> IF): two dwordx4 from one base.
__device__ __forceinline__ void load32_sc(const void* p, uint4v& a, uint4v& b) {
    asm volatile("global_load_dwordx4 %0, %2, off sc0 sc1\n\t"
                 "global_load_dwordx4 %1, %2, off offset:16 sc0 sc1\n\t"
                 "s_waitcnt vmcnt(0)"
                 : "=v"(a), "=v"(b) : "v"(p) : "memory");
}

__device__ __forceinline__ bool any_sent(const uint4v& a, const uint4v& b) {
    return a[0] == SENTINEL || a[1] == SENTINEL || a[2] == SENTINEL || a[3] == SENTINEL ||
           b[0] == SENTINEL || b[1] == SENTINEL || b[2] == SENTINEL || b[3] == SENTINEL;
}

// Poll 8 consecutive floats until none is the sentinel. Fast path: asm sc0 sc1
// loads; every 16th iteration falls back to __hip_atomic_load (guaranteed
// agent semantics) so progress never depends on the asm cache-bit assumption.
__device__ __forceinline__ void poll32(const float* p, uint4v& a, uint4v& b) {
    load32_sc(p, a, b);
    int k = 0;
    while (any_sent(a, b)) {
        if ((++k & 15) == 0) {
            const unsigned long long* q = (const unsigned long long*)p;
            unsigned long long q0 = __hip_atomic_load(q + 0, __ATOMIC_RELAXED, __HIP_MEMORY_SCOPE_AGENT);
            unsigned long long q1 = __hip_atomic_load(q + 1, __ATOMIC_RELAXED, __HIP_MEMORY_SCOPE_AGENT);
            unsigned long long q2 = __hip_atomic_load(q + 2, __ATOMIC_RELAXED, __HIP_MEMORY_SCOPE_AGENT);
            unsigned long long q3 = __hip_atomic_load(q + 3, __ATOMIC_RELAXED, __HIP_MEMORY_SCOPE_AGENT);
            a[0] = (unsigned)q0; a[1] = (unsigned)(q0 >> 32);
            a[2] = (unsigned)q1; a[3] = (unsigned)(q1 >> 32);
            b[0] = (unsigned)q2; b[1] = (unsigned)(q2 >> 32);
            b[2] = (unsigned)q3; b[3] = (unsigned)(q3 >> 32);
        } else {
            load32_sc(p, a, b);
        }
    }
}

// Phase 1: X_proj[t][r] = b_ih[r]+b_hh[r] + sum_e W_ih[r][e]*emb[x[t]][e]
// Grid (NRG, NSG). rowg==0 blocks also sentinel-clear MB steps t0+1..t0+15;
// (0,0) additionally fills MB[0] with 8 copies of h0. All re-done every call.
__global__ __launch_bounds__(TPB) void xproj_init_kernel(
    const int* __restrict__ x, const float* __restrict__ h0,
    const float* __restrict__ emb, const float* __restrict__ W_ih,
    const float* __restrict__ b_ih, const float* __restrict__ b_hh,
    float* __restrict__ ws) {
    const int rowg = blockIdx.x;      // 0..7
    const int sg   = blockIdx.y;      // 0..19
    const int tid  = threadIdx.x;
    const int t0   = sg * TS2;
    const int r    = rowg * TPB + tid;

    float* mb = ws + MB_OFF;

    if (rowg == 0) {
        unsigned* msb = (unsigned*)(mb + (size_t)(t0 + 1) * MB_STEP);
        for (int i = tid; i < TS2 * MB_STEP; i += TPB) msb[i] = SENTINEL;
        if (sg == 0) {
            for (int i = tid; i < MB_STEP; i += TPB) mb[i] = h0[i & (HID - 1)];
        }
    }

    __shared__ float e_lds[TS2][EMBD];
    for (int tt = 0; tt < TS2; ++tt) {
        const float* er = emb + (long long)x[t0 + tt] * EMBD;
        for (int i = tid; i < EMBD; i += TPB) e_lds[tt][i] = er[i];
    }
    __syncthreads();

    float acc[TS2];
    const float bsum = b_ih[r] + b_hh[r];
    #pragma unroll
    for (int tt = 0; tt < TS2; ++tt) acc[tt] = bsum;

    const float* wrow = W_ih + (size_t)r * EMBD;
    for (int e = 0; e < EMBD; e += 4) {
        const float4 w4 = *(const float4*)(wrow + e);
        #pragma unroll
        for (int tt = 0; tt < TS2; ++tt) {
            acc[tt] = fmaf(w4.x, e_lds[tt][e],     acc[tt]);
            acc[tt] = fmaf(w4.y, e_lds[tt][e + 1], acc[tt]);
            acc[tt] = fmaf(w4.z, e_lds[tt][e + 2], acc[tt]);
            acc[tt] = fmaf(w4.w, e_lds[tt][e + 3], acc[tt]);
        }
    }
    #pragma unroll
    for (int tt = 0; tt < TS2; ++tt)
        ws[(size_t)(t0 + tt) * G4 + r] = acc[tt];
}

// Phase 2: 32-WG persistent dataflow scan with replicated mailboxes.
// Wave 0 of each WG polls its mailbox copy (64 lanes x 32 B), fills LDS;
// raw s_barriers (no vmcnt drain) separate fill/compute; producers broadcast
// h within-wave via shuffles and scatter 16B slices to all 8 mailboxes with
// relaxed agent-scope atomic stores (the R1-proven visibility path).
__global__ __launch_bounds__(TPB, 1) void lstm_scan_kernel(
    const float* __restrict__ c0, const float* __restrict__ W_hh,
    const float* __restrict__ fc_w, const float* __restrict__ fc_b,
    float* __restrict__ ws, float* __restrict__ out) {
    const int tid  = threadIdx.x;
    const int wg   = blockIdx.x;
    const int v    = tid >> 6;     // wave id
    const int lane = tid & 63;
    const int g    = lane >> 4;    // group within wave
    const int li   = lane & 15;    // lane within group (column split)
    const int hidx = wg * 16 + v * 4 + g;
    const int mbi  = wg & (NMB - 1);

    float* mb       = ws + MB_OFF;     // [301][NMB][512]
    const float* xp = ws;              // [300][2048]

    __shared__ __align__(16) float h_lds[576];   // idx i -> i + 4*(i>>5)

    // W_hh slice in registers: wreg[gate][k] = W_hh[gate*512 + hidx][li*32 + k]
    float wreg[4][32];
    #pragma unroll
    for (int gate = 0; gate < 4; ++gate) {
        const float* wr = W_hh + ((size_t)gate * HID + hidx) * HID + li * 32;
        #pragma unroll
        for (int k = 0; k < 32; k += 4) {
            const float4 w4 = *(const float4*)(wr + k);
            wreg[gate][k] = w4.x; wreg[gate][k + 1] = w4.y;
            wreg[gate][k + 2] = w4.z; wreg[gate][k + 3] = w4.w;
        }
    }

    const bool upd = (li == 0);
    float c = upd ? c0[hidx] : 0.0f;

    for (int s = 0; s < NSTEP; ++s) {
        // X_proj loads issued early -> latency hidden under poll/barrier.
        float xi = 0.f, xf = 0.f, xg = 0.f, xo = 0.f;
        if (upd) {
            const float* xpt = xp + (size_t)s * G4 + hidx;
            xi = xpt[0]; xf = xpt[HID]; xg = xpt[2 * HID]; xo = xpt[3 * HID];
        }

        // Wave 0: poll this WG's mailbox copy and fill LDS (8 floats/lane).
        if (v == 0) {
            const float* src = mb + (size_t)s * MB_STEP + (size_t)mbi * HID + lane * 8;
            uint4v a, b;
            poll32(src, a, b);
            const int i0 = lane * 8;
            float4* dst = (float4*)&h_lds[i0 + ((i0 >> 5) << 2)];
            dst[0] = make_float4(__uint_as_float(a[0]), __uint_as_float(a[1]),
                                 __uint_as_float(a[2]), __uint_as_float(a[3]));
            dst[1] = make_float4(__uint_as_float(b[0]), __uint_as_float(b[1]),
                                 __uint_as_float(b[2]), __uint_as_float(b[3]));
        }
        asm volatile("s_waitcnt lgkmcnt(0)" ::: "memory");
        __builtin_amdgcn_s_barrier();          // barrier A: fill -> compute

        // 4 gate rows for hidx: 32 cols/lane + 4-stage butterfly.
        float sums[4];
        const float* hrow = &h_lds[li * 36];
        #pragma unroll
        for (int gate = 0; gate < 4; ++gate) {
            float acc = 0.0f;
            #pragma unroll
            for (int k = 0; k < 32; k += 4) {
                const float4 h4 = *(const float4*)(hrow + k);
                acc = fmaf(wreg[gate][k],     h4.x, acc);
                acc = fmaf(wreg[gate][k + 1], h4.y, acc);
                acc = fmaf(wreg[gate][k + 2], h4.z, acc);
                acc = fmaf(wreg[gate][k + 3], h4.w, acc);
            }
            acc += __shfl_xor(acc, 1);
            acc += __shfl_xor(acc, 2);
            acc += __shfl_xor(acc, 4);
            acc += __shfl_xor(acc, 8);
            sums[gate] = acc;
        }

        float hnew = 0.0f;
        if (upd) {
            const float iv = fsig(sums[0] + xi);
            const float fv = fsig(sums[1] + xf);
            const float gv = ftanh(sums[2] + xg);
            const float ov = fsig(sums[3] + xo);
            c = fv * c + iv * gv;
            hnew = ov * ftanh(c);
            if (s == NSTEP - 1) {
                out[1 + hidx] = hnew;
                out[1 + HID + hidx] = c;
            }
        }
        // Broadcast this wave's 4 new h values to all lanes (uniform flow).
        const float h0v = __shfl(hnew, 0);
        const float h1v = __shfl(hnew, 16);
        const float h2v = __shfl(hnew, 32);
        const float h3v = __shfl(hnew, 48);
        // Lanes 0..7 scatter the 16B slice to the 8 mailbox copies.
        if (lane < 8) {
            float* dst = mb + (size_t)(s + 1) * MB_STEP + (size_t)lane * HID
                       + wg * 16 + v * 4;
            __hip_atomic_store(dst + 0, h0v, __ATOMIC_RELAXED, __HIP_MEMORY_SCOPE_AGENT);
            __hip_atomic_store(dst + 1, h1v, __ATOMIC_RELAXED, __HIP_MEMORY_SCOPE_AGENT);
            __hip_atomic_store(dst + 2, h2v, __ATOMIC_RELAXED, __HIP_MEMORY_SCOPE_AGENT);
            __hip_atomic_store(dst + 3, h3v, __ATOMIC_RELAXED, __HIP_MEMORY_SCOPE_AGENT);
        }
        __builtin_amdgcn_sched_barrier(0);
        __builtin_amdgcn_s_barrier();          // barrier B: LDS reads done
    }

    // Epilogue: WG 0, wave 0 computes out[0] = sigmoid(fc_w . h_300 + fc_b).
    if (wg == 0 && v == 0) {
        const float* src = mb + (size_t)NSTEP * MB_STEP + lane * 8;  // copy 0
        uint4v a, b;
        poll32(src, a, b);
        const float* fw = fc_w + lane * 8;
        float p = __uint_as_float(a[0]) * fw[0] + __uint_as_float(a[1]) * fw[1]
                + __uint_as_float(a[2]) * fw[2] + __uint_as_float(a[3]) * fw[3]
                + __uint_as_float(b[0]) * fw[4] + __uint_as_float(b[1]) * fw[5]
                + __uint_as_float(b[2]) * fw[6] + __uint_as_float(b[3]) * fw[7];
        p += __shfl_xor(p, 1);
        p += __shfl_xor(p, 2);
        p += __shfl_xor(p, 4);
        p += __shfl_xor(p, 8);
        p += __shfl_xor(p, 16);
        p += __shfl_xor(p, 32);
        if (lane == 0) out[0] = fsig(p + fc_b[0]);
    }
}

extern "C" void kernel_launch(void* const* d_in, const int* in_sizes, int n_in,
                              void* d_out, int out_size, void* d_ws, size_t ws_size,
                              hipStream_t stream) {
    (void)in_sizes; (void)n_in; (void)out_size; (void)ws_size;
    const int*   x     = (const int*)d_in[0];
    const float* h0    = (const float*)d_in[1];
    const float* c0    = (const float*)d_in[2];
    const float* emb   = (const float*)d_in[3];
    const float* W_ih  = (const float*)d_in[4];
    const float* W_hh  = (const float*)d_in[5];
    const float* b_ih  = (const float*)d_in[6];
    const float* b_hh  = (const float*)d_in[7];
    const float* fc_w  = (const float*)d_in[8];
    const float* fc_b  = (const float*)d_in[9];
    float* out = (float*)d_out;
    float* ws  = (float*)d_ws;

    xproj_init_kernel<<<dim3(NRG, NSG), dim3(TPB), 0, stream>>>(
        x, h0, emb, W_ih, b_ih, b_hh, ws);
    lstm_scan_kernel<<<dim3(NWG), dim3(TPB), 0, stream>>>(
        c0, W_hh, fc_w, fc_b, ws, out);
}